// Round 2
// baseline (275.316 us; speedup 1.0000x reference)
//
#include <hip/hip_runtime.h>
#include <hip/hip_bf16.h>
#include <stdint.h>
#include <math.h>

#define SEQ 4096
#define DIM 1024
#define NHEADS 16
#define DHEAD 64
#define INNER 1024

typedef __hip_bfloat16 bf16;
typedef __attribute__((ext_vector_type(8))) short short8;
typedef __attribute__((ext_vector_type(4))) float floatx4;

// async global->LDS, 16B per lane; lane i's 16B lands at dest + i*16.
__device__ __forceinline__ void gll16(const bf16* g, bf16* l) {
    __builtin_amdgcn_global_load_lds(
        (const __attribute__((address_space(1))) unsigned int*)g,
        (__attribute__((address_space(3))) unsigned int*)l,
        16, 0, 0);
}

__device__ __forceinline__ unsigned short f2bf_bits(float f) {
    bf16 h = __float2bfloat16(f);
    return *reinterpret_cast<unsigned short*>(&h);
}

__device__ __forceinline__ uint2 pack4bf(float a, float b, float c, float d) {
    __hip_bfloat162 lo = __float22bfloat162_rn(float2{a, b});
    __hip_bfloat162 hi = __float22bfloat162_rn(float2{c, d});
    uint2 r;
    r.x = *reinterpret_cast<unsigned*>(&lo);
    r.y = *reinterpret_cast<unsigned*>(&hi);
    return r;
}

// ---------------- prep: z=0..3 weight transpose+convert; z=4 x convert ----------------
__global__ __launch_bounds__(256) void prep_kernel(
        const float* __restrict__ x, const float* __restrict__ W0,
        const float* __restrict__ W1, const float* __restrict__ W2,
        const float* __restrict__ W3, bf16* __restrict__ xb,
        bf16* __restrict__ T0, bf16* __restrict__ T1,
        bf16* __restrict__ T2, bf16* __restrict__ T3) {
    const int tid = threadIdx.x + threadIdx.y * blockDim.x;  // 0..255
    if (blockIdx.z == 4) {
        // convert x: block (bx,by) -> chunk (by*32+bx) of 4096 floats
        int chunk = blockIdx.y * 32 + blockIdx.x;
        int base = chunk * 4096 + tid * 4;
        #pragma unroll
        for (int r = 0; r < 4; r++) {
            int i = base + r * 1024;
            float4 f = *reinterpret_cast<const float4*>(x + i);
            unsigned long long p = (unsigned long long)f2bf_bits(f.x)
                                 | ((unsigned long long)f2bf_bits(f.y) << 16)
                                 | ((unsigned long long)f2bf_bits(f.z) << 32)
                                 | ((unsigned long long)f2bf_bits(f.w) << 48);
            *reinterpret_cast<unsigned long long*>(xb + i) = p;
        }
        return;
    }
    const float* W; bf16* T;
    switch (blockIdx.z) {
        case 0:  W = W0; T = T0; break;
        case 1:  W = W1; T = T1; break;
        case 2:  W = W2; T = T2; break;
        default: W = W3; T = T3; break;
    }
    __shared__ float tile[32][33];
    int k0 = blockIdx.x * 32, n0 = blockIdx.y * 32;
    int tx = threadIdx.x, ty = threadIdx.y;
    #pragma unroll
    for (int i = 0; i < 4; i++)
        tile[ty + 8 * i][tx] = W[(size_t)(k0 + ty + 8 * i) * 1024 + n0 + tx];
    __syncthreads();
    #pragma unroll
    for (int i = 0; i < 4; i++)
        T[(size_t)(n0 + ty + 8 * i) * 1024 + k0 + tx] = __float2bfloat16(tile[tx][ty + 8 * i]);
}

// ---------------- 128x128 bf16 MFMA GEMM tile body (K=1024), m97-style ----------------
__device__ __forceinline__ void gemm128_body(const bf16* __restrict__ A,
                                             const bf16* __restrict__ Bt,
                                             int m0, int n0, floatx4 acc[4][4]) {
    __shared__ __align__(16) bf16 As[8192];
    __shared__ __align__(16) bf16 Bs[8192];
    const int tid = threadIdx.x;
    const int wave = tid >> 6;
    const int lane = tid & 63;
    const int l15 = lane & 15;
    const int quad = lane >> 4;

    #pragma unroll
    for (int i = 0; i < 4; i++)
        #pragma unroll
        for (int j = 0; j < 4; j++)
            acc[i][j] = (floatx4){0.f, 0.f, 0.f, 0.f};

    for (int k0 = 0; k0 < 1024; k0 += 64) {
        __syncthreads();
        #pragma unroll
        for (int j = 0; j < 4; j++) {
            int t = wave * 4 + j;
            int row = (t >> 1) * 16 + l15;
            int kb = (t & 1) * 32 + quad * 8;
            gll16(A + (size_t)(m0 + row) * 1024 + k0 + kb, &As[t * 512]);
            gll16(Bt + (size_t)(n0 + row) * 1024 + k0 + kb, &Bs[t * 512]);
        }
        __syncthreads();
        #pragma unroll
        for (int ks = 0; ks < 2; ks++) {
            short8 af[4], bfr[4];
            #pragma unroll
            for (int i = 0; i < 4; i++)
                af[i] = *reinterpret_cast<const short8*>(
                    &As[((((wave >> 1) * 4 + i) * 2 + ks) * 512) + lane * 8]);
            #pragma unroll
            for (int j = 0; j < 4; j++)
                bfr[j] = *reinterpret_cast<const short8*>(
                    &Bs[((((wave & 1) * 4 + j) * 2 + ks) * 512) + lane * 8]);
            #pragma unroll
            for (int i = 0; i < 4; i++)
                #pragma unroll
                for (int j = 0; j < 4; j++)
                    acc[i][j] = __builtin_amdgcn_mfma_f32_16x16x32_bf16(af[i], bfr[j], acc[i][j], 0, 0, 0);
        }
    }
}

// ---------------- QKV projection ----------------
// z=0: Q (scaled by beta*log2e so attention uses raw v_exp_f32; [h][seq][64])
// z=1: K ([h][seq][64])
// z=2: V written TRANSPOSED directly: Vt[h][d][seq] (b64 packed stores).
__global__ __launch_bounds__(256) void qkv_gemm_kernel(
        const bf16* __restrict__ xb,
        const bf16* __restrict__ Wqt, const bf16* __restrict__ Wkt, const bf16* __restrict__ Wvt,
        bf16* __restrict__ Qh, bf16* __restrict__ Kh, bf16* __restrict__ Vt) {
    const bf16* Bt;
    if (blockIdx.z == 0)      Bt = Wqt;
    else if (blockIdx.z == 1) Bt = Wkt;
    else                      Bt = Wvt;
    int n0 = blockIdx.x * 128, m0 = blockIdx.y * 128;
    floatx4 acc[4][4];
    gemm128_body(xb, Bt, m0, n0, acc);

    const int tid = threadIdx.x, wave = tid >> 6, lane = tid & 63;
    const int l15 = lane & 15, quad = lane >> 4;
    const int wm = (wave >> 1) * 64, wn = (wave & 1) * 64;
    if (blockIdx.z == 2) {
        #pragma unroll
        for (int i = 0; i < 4; i++)
            #pragma unroll
            for (int j = 0; j < 4; j++) {
                int col = n0 + wn + j * 16 + l15;
                int h = col >> 6, d = col & 63;
                int row0 = m0 + wm + i * 16 + quad * 4;
                uint2 v = pack4bf(acc[i][j][0], acc[i][j][1], acc[i][j][2], acc[i][j][3]);
                *reinterpret_cast<uint2*>(Vt + ((size_t)h * DHEAD + d) * SEQ + row0) = v;
            }
    } else {
        bf16* O = (blockIdx.z == 0) ? Qh : Kh;
        float scale = (blockIdx.z == 0) ? 0.125f * 1.4426950408889634f : 1.0f;
        #pragma unroll
        for (int i = 0; i < 4; i++)
            #pragma unroll
            for (int j = 0; j < 4; j++) {
                int col = n0 + wn + j * 16 + l15;
                int h = col >> 6, d = col & 63;
                #pragma unroll
                for (int r = 0; r < 4; r++) {
                    int row = m0 + wm + i * 16 + quad * 4 + r;
                    O[((size_t)h * SEQ + row) * DHEAD + d] = __float2bfloat16(acc[i][j][r] * scale);
                }
            }
    }
}

// ---------------- output projection: out = Oa @ Wo + bo (fp32 out) ----------------
__global__ __launch_bounds__(256) void out_gemm_kernel(
        const bf16* __restrict__ Oa, const bf16* __restrict__ Wot,
        const float* __restrict__ bo, float* __restrict__ out) {
    int n0 = blockIdx.x * 128, m0 = blockIdx.y * 128;
    floatx4 acc[4][4];
    gemm128_body(Oa, Wot, m0, n0, acc);

    const int tid = threadIdx.x, wave = tid >> 6, lane = tid & 63;
    const int l15 = lane & 15, quad = lane >> 4;
    const int wm = (wave >> 1) * 64, wn = (wave & 1) * 64;
    #pragma unroll
    for (int i = 0; i < 4; i++)
        #pragma unroll
        for (int j = 0; j < 4; j++) {
            int col = n0 + wn + j * 16 + l15;
            float b = bo[col];
            #pragma unroll
            for (int r = 0; r < 4; r++) {
                int row = m0 + wm + i * 16 + quad * 4 + r;
                out[(size_t)row * DIM + col] = acc[i][j][r] + b;
            }
        }
}

// ---------------- causal flash attention (R10: 32 q-rows/wave, LDS-intensity fix) ----------------
// POST-MORTEM R9: dbuf/occupancy/schedule restructure was NEUTRAL (90 µs both,
// MfmaUtil 15% both) -> kernel is LDS-BANDWIDTH-bound: 18 b128 reads fed only
// 16 MFMAs (1.28 KB LDS/MFMA); 3.3 GB total LDS traffic ~= the 90 µs at
// measured b128 throughput. Fix = raise arithmetic intensity per LDS byte:
//   * each wave owns 32 q-rows (two 16-row Q register fragment groups).
//     Every K-frag read now feeds 2 MFMAs (one per q-group); every av/bp
//     likewise: 20 reads -> 32 MFMAs = 0.64 KB/MFMA (2.0x better).
//   * block covers 128 q-rows -> 512 blocks, block-tile count halves,
//     total LDS traffic 3.3 -> 1.9 GB. Staging bytes per q-row halve too.
//   * co-resident pairs (id, id+256) -> ranks (r, r+16) -> qtiles (r, 31-r):
//     per-CU pair sums 66 tile-units (balanced). head = id&15 keeps
//     2-heads/XCD L2 pinning (FETCH 12 MB).
//   * LDS 48 KB; launch_bounds(256,2) (need ~140 VGPR; min-4-waves would spill).
//   * keep R9 dbuf + prefetch-before-compute + 1 barrier/tile (harmless).
// Sᵀ = K·Qᵀ; Q pre-scaled by beta*log2e => p = v_exp_f32(s) via
// __builtin_amdgcn_exp2f — do NOT use exp2f (libcall, +15 µs R8).
// DO NOT: drop staging (R6), V in regs (R7 spill).
__global__ __launch_bounds__(256, 2) void attention_kernel(
        const bf16* __restrict__ Qh, const bf16* __restrict__ Kh,
        const bf16* __restrict__ Vt, bf16* __restrict__ Oa) {
    __shared__ __align__(16) bf16 Ksh[2][4096];  // 2 x 8 KB: frag t = keygrp*2 + khalf
    __shared__ __align__(16) bf16 Vsh[2][4096];  // 2 x 8 KB: frag t = dgrp*2 + kseg
    __shared__ __align__(16) bf16 Ps[4][2048];   // 4 KB/wave: region = s*2 + g
    const int tid = threadIdx.x, wave = tid >> 6, lane = tid & 63;
    const int l15 = lane & 15, quad = lane >> 4;
    const int id = blockIdx.x;
    const int head = id & 15;                    // XCD id&7 serves heads {h, h+8}
    const int rk = id >> 4;                      // 0..31
    const int qtile = (rk < 16) ? rk : 47 - rk;  // pair (r, r+16) -> (r, 31-r)
    const int qbase = qtile * 128;
    const int qw = qbase + wave * 32;            // wave's 32 q-rows
    const size_t hoff = (size_t)head * SEQ * DHEAD;
    const bf16* Qb = Qh + hoff;
    const bf16* Kb = Kh + hoff;
    const bf16* Vb = Vt + hoff;                  // [d][seq]

    // Q as B-operand fragments: g = 16-row group, s = k-half along d
    short8 bq[2][2];
    #pragma unroll
    for (int g = 0; g < 2; g++)
        #pragma unroll
        for (int s = 0; s < 2; s++)
            bq[g][s] = *reinterpret_cast<const short8*>(
                Qb + (size_t)(qw + g * 16 + l15) * DHEAD + s * 32 + quad * 8);

    floatx4 acc_o[2][4];                         // Oᵀ per q-group: d = c*16+quad*4+r, q = l15
    #pragma unroll
    for (int g = 0; g < 2; g++)
        #pragma unroll
        for (int c = 0; c < 4; c++) acc_o[g][c] = (floatx4){0.f, 0.f, 0.f, 0.f};
    float l_part[2] = {0.f, 0.f};                // per-lane softmax denom partials

    // per-wave stage of one 64-key K tile + V tile into buffer `buf`
    auto stage = [&](int buf, int kbase) {
        #pragma unroll
        for (int j = 0; j < 2; j++) {
            int t = wave * 2 + j;                // t = 0..7 across 4 waves
            gll16(Kb + (size_t)(kbase + (t >> 1) * 16 + l15) * DHEAD + (t & 1) * 32 + quad * 8,
                  &Ksh[buf][t * 512]);
            gll16(Vb + (size_t)((t >> 1) * 16 + l15) * SEQ + kbase + (t & 1) * 32 + quad * 8,
                  &Vsh[buf][t * 512]);
        }
    };

    const int ntiles = 2 * qtile + 2;            // keys 0..qtile*128+127 exactly
    stage(0, 0);
    __syncthreads();                             // vmcnt(0) drain + tile 0 visible
    int cur = 0;
    for (int kt = 0; kt < ntiles; kt++) {
        const int kbase = kt * 64;
        if (kt + 1 < ntiles) stage(cur ^ 1, (kt + 1) * 64);  // async prefetch

        // Sᵀ = K·Qᵀ: 8 K-frag reads feed 16 MFMAs (2 q-groups)
        floatx4 st[2][4];
        #pragma unroll
        for (int g = 0; g < 2; g++)
            #pragma unroll
            for (int c = 0; c < 4; c++) st[g][c] = (floatx4){0.f, 0.f, 0.f, 0.f};
        __builtin_amdgcn_s_setprio(1);
        #pragma unroll
        for (int c = 0; c < 4; c++) {
            short8 ak0 = *reinterpret_cast<const short8*>(&Ksh[cur][(c * 2 + 0) * 512 + lane * 8]);
            short8 ak1 = *reinterpret_cast<const short8*>(&Ksh[cur][(c * 2 + 1) * 512 + lane * 8]);
            st[0][c] = __builtin_amdgcn_mfma_f32_16x16x32_bf16(ak0, bq[0][0], st[0][c], 0, 0, 0);
            st[0][c] = __builtin_amdgcn_mfma_f32_16x16x32_bf16(ak1, bq[0][1], st[0][c], 0, 0, 0);
            st[1][c] = __builtin_amdgcn_mfma_f32_16x16x32_bf16(ak0, bq[1][0], st[1][c], 0, 0, 0);
            st[1][c] = __builtin_amdgcn_mfma_f32_16x16x32_bf16(ak1, bq[1][1], st[1][c], 0, 0, 0);
        }
        __builtin_amdgcn_s_setprio(0);
        // causal mask: key = kbase + c*16 + quad*4 + r, q = qw + g*16 + l15
        #pragma unroll
        for (int g = 0; g < 2; g++) {
            if (kbase + 63 > qw + g * 16) {      // wave-uniform per group
                int base0 = kbase + quad * 4 - (qw + g * 16) - l15;
                #pragma unroll
                for (int c = 0; c < 4; c++) {
                    int base = base0 + c * 16;
                    #pragma unroll
                    for (int r = 0; r < 4; r++)
                        if (base + r > 0) st[g][c][r] = -1e30f;
                }
            }
        }
        // p = 2^s: raw v_exp_f32 (masked -> 2^-1e30 = 0); per-lane denom; pack Ps
        #pragma unroll
        for (int g = 0; g < 2; g++)
            #pragma unroll
            for (int c = 0; c < 4; c++) {
                float p0 = __builtin_amdgcn_exp2f(st[g][c][0]);
                float p1 = __builtin_amdgcn_exp2f(st[g][c][1]);
                float p2 = __builtin_amdgcn_exp2f(st[g][c][2]);
                float p3 = __builtin_amdgcn_exp2f(st[g][c][3]);
                l_part[g] += (p0 + p1) + (p2 + p3);
                int elem = ((c >> 1) * 2 + g) * 512
                         + (l15 + 16 * ((c & 1) * 2 + (quad >> 1))) * 8 + (quad & 1) * 4;
                *reinterpret_cast<uint2*>(&Ps[wave][elem]) = pack4bf(p0, p1, p2, p3);
            }
        // Oᵀ += Vᵀ·Pᵀ: 12 reads feed 16 MFMAs (2 q-groups share each av)
        __builtin_amdgcn_s_setprio(1);
        #pragma unroll
        for (int s = 0; s < 2; s++) {
            short8 bp0 = *reinterpret_cast<const short8*>(&Ps[wave][(s * 2 + 0) * 512 + lane * 8]);
            short8 bp1 = *reinterpret_cast<const short8*>(&Ps[wave][(s * 2 + 1) * 512 + lane * 8]);
            #pragma unroll
            for (int c = 0; c < 4; c++) {
                short8 av = *reinterpret_cast<const short8*>(&Vsh[cur][(c * 2 + s) * 512 + lane * 8]);
                acc_o[0][c] = __builtin_amdgcn_mfma_f32_16x16x32_bf16(av, bp0, acc_o[0][c], 0, 0, 0);
                acc_o[1][c] = __builtin_amdgcn_mfma_f32_16x16x32_bf16(av, bp1, acc_o[1][c], 0, 0, 0);
            }
        }
        __builtin_amdgcn_s_setprio(0);

        __syncthreads();                         // readers done + prefetch drained
        cur ^= 1;
    }
    // denom: sum the 4 quad-lanes holding this q-row (per group)
    #pragma unroll
    for (int g = 0; g < 2; g++) {
        float l = l_part[g];
        l += __shfl_xor(l, 16, 64);
        l += __shfl_xor(l, 32, 64);
        float rcp = 1.0f / l;
        const int q = qw + g * 16 + l15;
        #pragma unroll
        for (int c = 0; c < 4; c++) {
            uint2 v = pack4bf(acc_o[g][c][0] * rcp, acc_o[g][c][1] * rcp,
                              acc_o[g][c][2] * rcp, acc_o[g][c][3] * rcp);
            *reinterpret_cast<uint2*>(Oa + (size_t)q * INNER + head * DHEAD + c * 16 + quad * 4) = v;
        }
    }
}

extern "C" void kernel_launch(void* const* d_in, const int* in_sizes, int n_in,
                              void* d_out, int out_size, void* d_ws, size_t ws_size,
                              hipStream_t stream) {
    const float* x  = (const float*)d_in[0];
    const float* Wq = (const float*)d_in[1];
    const float* Wk = (const float*)d_in[2];
    const float* Wv = (const float*)d_in[3];
    const float* Wo = (const float*)d_in[4];
    const float* bo = (const float*)d_in[5];
    float* out = (float*)d_out;

    char* ws = (char*)d_ws;
    size_t off = 0;
    bf16* xb  = (bf16*)(ws + off); off += (size_t)SEQ * DIM * 2;
    bf16* Wqt = (bf16*)(ws + off); off += (size_t)DIM * INNER * 2;
    bf16* Wkt = (bf16*)(ws + off); off += (size_t)DIM * INNER * 2;
    bf16* Wvt = (bf16*)(ws + off); off += (size_t)DIM * INNER * 2;
    bf16* Wot = (bf16*)(ws + off); off += (size_t)INNER * DIM * 2;
    bf16* Qh  = (bf16*)(ws + off); off += (size_t)NHEADS * SEQ * DHEAD * 2;
    bf16* Kh  = (bf16*)(ws + off); off += (size_t)NHEADS * SEQ * DHEAD * 2;
    bf16* Vtr = (bf16*)(ws + off); off += (size_t)NHEADS * DHEAD * SEQ * 2;
    bf16* Oa  = (bf16*)(ws + off); off += (size_t)SEQ * INNER * 2;  // ~48 MB total

    prep_kernel<<<dim3(32, 32, 5), dim3(32, 8), 0, stream>>>(x, Wq, Wk, Wv, Wo,
                                                             xb, Wqt, Wkt, Wvt, Wot);
    qkv_gemm_kernel<<<dim3(8, 32, 3), 256, 0, stream>>>(xb, Wqt, Wkt, Wvt, Qh, Kh, Vtr);
    attention_kernel<<<512, 256, 0, stream>>>(Qh, Kh, Vtr, Oa);
    out_gemm_kernel<<<dim3(8, 32), 256, 0, stream>>>(Oa, Wot, bo, out);
}

// Round 3
// 249.893 us; speedup vs baseline: 1.1017x; 1.1017x over previous
//
#include <hip/hip_runtime.h>
#include <hip/hip_bf16.h>
#include <stdint.h>
#include <math.h>

#define SEQ 4096
#define DIM 1024
#define NHEADS 16
#define DHEAD 64
#define INNER 1024

typedef __hip_bfloat16 bf16;
typedef __attribute__((ext_vector_type(8))) short short8;
typedef __attribute__((ext_vector_type(4))) float floatx4;

// async global->LDS, 16B per lane; lane i's 16B lands at dest + i*16.
__device__ __forceinline__ void gll16(const bf16* g, bf16* l) {
    __builtin_amdgcn_global_load_lds(
        (const __attribute__((address_space(1))) unsigned int*)g,
        (__attribute__((address_space(3))) unsigned int*)l,
        16, 0, 0);
}

__device__ __forceinline__ unsigned short f2bf_bits(float f) {
    bf16 h = __float2bfloat16(f);
    return *reinterpret_cast<unsigned short*>(&h);
}

__device__ __forceinline__ uint2 pack4bf(float a, float b, float c, float d) {
    __hip_bfloat162 lo = __float22bfloat162_rn(float2{a, b});
    __hip_bfloat162 hi = __float22bfloat162_rn(float2{c, d});
    uint2 r;
    r.x = *reinterpret_cast<unsigned*>(&lo);
    r.y = *reinterpret_cast<unsigned*>(&hi);
    return r;
}

// ---------------- prep: z=0..3 weight transpose+convert; z=4 x convert ----------------
__global__ __launch_bounds__(256) void prep_kernel(
        const float* __restrict__ x, const float* __restrict__ W0,
        const float* __restrict__ W1, const float* __restrict__ W2,
        const float* __restrict__ W3, bf16* __restrict__ xb,
        bf16* __restrict__ T0, bf16* __restrict__ T1,
        bf16* __restrict__ T2, bf16* __restrict__ T3) {
    const int tid = threadIdx.x + threadIdx.y * blockDim.x;  // 0..255
    if (blockIdx.z == 4) {
        // convert x: block (bx,by) -> chunk (by*32+bx) of 4096 floats
        int chunk = blockIdx.y * 32 + blockIdx.x;
        int base = chunk * 4096 + tid * 4;
        #pragma unroll
        for (int r = 0; r < 4; r++) {
            int i = base + r * 1024;
            float4 f = *reinterpret_cast<const float4*>(x + i);
            unsigned long long p = (unsigned long long)f2bf_bits(f.x)
                                 | ((unsigned long long)f2bf_bits(f.y) << 16)
                                 | ((unsigned long long)f2bf_bits(f.z) << 32)
                                 | ((unsigned long long)f2bf_bits(f.w) << 48);
            *reinterpret_cast<unsigned long long*>(xb + i) = p;
        }
        return;
    }
    const float* W; bf16* T;
    switch (blockIdx.z) {
        case 0:  W = W0; T = T0; break;
        case 1:  W = W1; T = T1; break;
        case 2:  W = W2; T = T2; break;
        default: W = W3; T = T3; break;
    }
    __shared__ float tile[32][33];
    int k0 = blockIdx.x * 32, n0 = blockIdx.y * 32;
    int tx = threadIdx.x, ty = threadIdx.y;
    #pragma unroll
    for (int i = 0; i < 4; i++)
        tile[ty + 8 * i][tx] = W[(size_t)(k0 + ty + 8 * i) * 1024 + n0 + tx];
    __syncthreads();
    #pragma unroll
    for (int i = 0; i < 4; i++)
        T[(size_t)(n0 + ty + 8 * i) * 1024 + k0 + tx] = __float2bfloat16(tile[tx][ty + 8 * i]);
}

// ---------------- 128x128 bf16 MFMA GEMM tile body (K=1024), m97-style ----------------
__device__ __forceinline__ void gemm128_body(const bf16* __restrict__ A,
                                             const bf16* __restrict__ Bt,
                                             int m0, int n0, floatx4 acc[4][4]) {
    __shared__ __align__(16) bf16 As[8192];
    __shared__ __align__(16) bf16 Bs[8192];
    const int tid = threadIdx.x;
    const int wave = tid >> 6;
    const int lane = tid & 63;
    const int l15 = lane & 15;
    const int quad = lane >> 4;

    #pragma unroll
    for (int i = 0; i < 4; i++)
        #pragma unroll
        for (int j = 0; j < 4; j++)
            acc[i][j] = (floatx4){0.f, 0.f, 0.f, 0.f};

    for (int k0 = 0; k0 < 1024; k0 += 64) {
        __syncthreads();
        #pragma unroll
        for (int j = 0; j < 4; j++) {
            int t = wave * 4 + j;
            int row = (t >> 1) * 16 + l15;
            int kb = (t & 1) * 32 + quad * 8;
            gll16(A + (size_t)(m0 + row) * 1024 + k0 + kb, &As[t * 512]);
            gll16(Bt + (size_t)(n0 + row) * 1024 + k0 + kb, &Bs[t * 512]);
        }
        __syncthreads();
        #pragma unroll
        for (int ks = 0; ks < 2; ks++) {
            short8 af[4], bfr[4];
            #pragma unroll
            for (int i = 0; i < 4; i++)
                af[i] = *reinterpret_cast<const short8*>(
                    &As[((((wave >> 1) * 4 + i) * 2 + ks) * 512) + lane * 8]);
            #pragma unroll
            for (int j = 0; j < 4; j++)
                bfr[j] = *reinterpret_cast<const short8*>(
                    &Bs[((((wave & 1) * 4 + j) * 2 + ks) * 512) + lane * 8]);
            #pragma unroll
            for (int i = 0; i < 4; i++)
                #pragma unroll
                for (int j = 0; j < 4; j++)
                    acc[i][j] = __builtin_amdgcn_mfma_f32_16x16x32_bf16(af[i], bfr[j], acc[i][j], 0, 0, 0);
        }
    }
}

// ---------------- QKV projection ----------------
// z=0: Q (scaled by beta*log2e so attention uses raw v_exp_f32; [h][seq][64])
// z=1: K ([h][seq][64])
// z=2: V written TRANSPOSED directly: Vt[h][d][seq] (b64 packed stores).
__global__ __launch_bounds__(256) void qkv_gemm_kernel(
        const bf16* __restrict__ xb,
        const bf16* __restrict__ Wqt, const bf16* __restrict__ Wkt, const bf16* __restrict__ Wvt,
        bf16* __restrict__ Qh, bf16* __restrict__ Kh, bf16* __restrict__ Vt) {
    const bf16* Bt;
    if (blockIdx.z == 0)      Bt = Wqt;
    else if (blockIdx.z == 1) Bt = Wkt;
    else                      Bt = Wvt;
    int n0 = blockIdx.x * 128, m0 = blockIdx.y * 128;
    floatx4 acc[4][4];
    gemm128_body(xb, Bt, m0, n0, acc);

    const int tid = threadIdx.x, wave = tid >> 6, lane = tid & 63;
    const int l15 = lane & 15, quad = lane >> 4;
    const int wm = (wave >> 1) * 64, wn = (wave & 1) * 64;
    if (blockIdx.z == 2) {
        #pragma unroll
        for (int i = 0; i < 4; i++)
            #pragma unroll
            for (int j = 0; j < 4; j++) {
                int col = n0 + wn + j * 16 + l15;
                int h = col >> 6, d = col & 63;
                int row0 = m0 + wm + i * 16 + quad * 4;
                uint2 v = pack4bf(acc[i][j][0], acc[i][j][1], acc[i][j][2], acc[i][j][3]);
                *reinterpret_cast<uint2*>(Vt + ((size_t)h * DHEAD + d) * SEQ + row0) = v;
            }
    } else {
        bf16* O = (blockIdx.z == 0) ? Qh : Kh;
        float scale = (blockIdx.z == 0) ? 0.125f * 1.4426950408889634f : 1.0f;
        #pragma unroll
        for (int i = 0; i < 4; i++)
            #pragma unroll
            for (int j = 0; j < 4; j++) {
                int col = n0 + wn + j * 16 + l15;
                int h = col >> 6, d = col & 63;
                #pragma unroll
                for (int r = 0; r < 4; r++) {
                    int row = m0 + wm + i * 16 + quad * 4 + r;
                    O[((size_t)h * SEQ + row) * DHEAD + d] = __float2bfloat16(acc[i][j][r] * scale);
                }
            }
    }
}

// ---------------- output projection: out = Oa @ Wo + bo (fp32 out) ----------------
__global__ __launch_bounds__(256) void out_gemm_kernel(
        const bf16* __restrict__ Oa, const bf16* __restrict__ Wot,
        const float* __restrict__ bo, float* __restrict__ out) {
    int n0 = blockIdx.x * 128, m0 = blockIdx.y * 128;
    floatx4 acc[4][4];
    gemm128_body(Oa, Wot, m0, n0, acc);

    const int tid = threadIdx.x, wave = tid >> 6, lane = tid & 63;
    const int l15 = lane & 15, quad = lane >> 4;
    const int wm = (wave >> 1) * 64, wn = (wave & 1) * 64;
    #pragma unroll
    for (int i = 0; i < 4; i++)
        #pragma unroll
        for (int j = 0; j < 4; j++) {
            int col = n0 + wn + j * 16 + l15;
            float b = bo[col];
            #pragma unroll
            for (int r = 0; r < 4; r++) {
                int row = m0 + wm + i * 16 + quad * 4 + r;
                out[(size_t)row * DIM + col] = acc[i][j][r] + b;
            }
        }
}

// ---------------- causal flash attention (R11: split-key, additive partials) ----------------
// POST-MORTEM R9/R10: schedule/LDS-intensity changes neutral-or-worse; fit of
// {R4,R9,R10} to dur = crit_iters x (C*content + B) gives B~2700cy, C~640cy:
// SERIAL-LATENCY bound on the longest block (64-tile chain runs mostly alone
// at 4 waves/CU near the end -> nothing hides B). Fix: halve the chain.
// Softmax here has NO max-subtraction (raw exp2 of pre-scaled scores), so
// partial unnormalized (O, l) over disjoint key ranges are DIRECTLY ADDITIVE.
//   * qt >= 32 split into chunk0 (keys 0..2047) + chunk1 (keys 2048..) as
//     separate blocks -> max serial chain 32 tiles. Grid 1536 blocks,
//     longest-first id order, fine lengths -> dynamic balancing.
//   * split chunks write unnormalized fp32 O + l partials; combine_kernel
//     sums+normalizes rows 2048..4095. Unsplit tiles finalize in-kernel.
//   * per-wave structure = R9 (proven): 16 q-rows/wave, BK=64 dbuf,
//     1 barrier/tile, 40KB LDS -> 4 blocks/CU, head = id&15 L2 pinning.
// Sᵀ = K·Qᵀ; p = v_exp_f32(s) via __builtin_amdgcn_exp2f — do NOT use exp2f
// (libcall, +15 µs R8). DO NOT: drop staging (R6), V in regs (R7 spill),
// 32 q-rows/wave at 2 blk/CU (R10, latency-exposed).
__global__ __launch_bounds__(256, 4) void attention_kernel(
        const bf16* __restrict__ Qh, const bf16* __restrict__ Kh,
        const bf16* __restrict__ Vt, bf16* __restrict__ Oa,
        float* __restrict__ Op0, float* __restrict__ Op1,
        float* __restrict__ L0, float* __restrict__ L1) {
    __shared__ __align__(16) bf16 Ksh[2][4096];  // 2 x 8 KB: frag t = keygrp*2 + khalf
    __shared__ __align__(16) bf16 Vsh[2][4096];  // 2 x 8 KB: frag t = dgrp*2 + kseg
    __shared__ __align__(16) bf16 Ps[4][1024];   // 2 KB/wave: frag s = key/32
    const int tid = threadIdx.x, wave = tid >> 6, lane = tid & 63;
    const int l15 = lane & 15, quad = lane >> 4;
    const int id = blockIdx.x;
    const int head = id & 15;                    // XCD id&7 serves heads {h, h+8}
    const int rk = id >> 4;                      // 0..95
    // piece map, longest-first: rk<32 -> (qt=32+rk, chunk0, len 32);
    // rk>=32: pair=(rk-32)>>1; even -> (qt=63-pair, chunk1, len 32-pair);
    //                          odd  -> (qt=31-pair, single, len 32-pair).
    int qt, ck;
    if (rk < 32) { qt = 32 + rk; ck = 0; }
    else {
        int j = rk - 32, pair = j >> 1;
        if ((j & 1) == 0) { qt = 63 - pair; ck = 1; }
        else              { qt = 31 - pair; ck = 0; }
    }
    const int ktile0 = ck ? 32 : 0;
    const int ktile1 = (qt < 32) ? (qt + 1) : (ck ? (qt + 1) : 32);
    const int qw = qt * 64 + wave * 16;          // wave's q-row base
    const size_t hoff = (size_t)head * SEQ * DHEAD;
    const bf16* Qb = Qh + hoff;
    const bf16* Kb = Kh + hoff;
    const bf16* Vb = Vt + hoff;                  // [d][seq]

    // Q as B-operand fragments: lane n = l15 -> q-row qw+l15, k along d
    short8 bq[2];
    #pragma unroll
    for (int s = 0; s < 2; s++)
        bq[s] = *reinterpret_cast<const short8*>(
            Qb + (size_t)(qw + l15) * DHEAD + s * 32 + quad * 8);

    floatx4 acc_o[4];                            // Oᵀ: d = c*16+quad*4+r, q = l15
    #pragma unroll
    for (int c = 0; c < 4; c++) acc_o[c] = (floatx4){0.f, 0.f, 0.f, 0.f};
    float l_part = 0.f;                          // per-lane softmax denom partial

    // per-wave stage of one 64-key K tile + V tile into buffer `buf`
    auto stage = [&](int buf, int kbase) {
        #pragma unroll
        for (int j = 0; j < 2; j++) {
            int t = wave * 2 + j;                // t = 0..7 across 4 waves
            gll16(Kb + (size_t)(kbase + (t >> 1) * 16 + l15) * DHEAD + (t & 1) * 32 + quad * 8,
                  &Ksh[buf][t * 512]);
            gll16(Vb + (size_t)((t >> 1) * 16 + l15) * SEQ + kbase + (t & 1) * 32 + quad * 8,
                  &Vsh[buf][t * 512]);
        }
    };

    stage(0, ktile0 * 64);
    __syncthreads();                             // vmcnt(0) drain + first tile visible
    int cur = 0;
    for (int kt = ktile0; kt < ktile1; kt++) {
        const int kbase = kt * 64;
        if (kt + 1 < ktile1) stage(cur ^ 1, (kt + 1) * 64);  // async prefetch

        // Sᵀ = K·Qᵀ: linear conflict-free b128 LDS reads
        floatx4 st[4];
        #pragma unroll
        for (int c = 0; c < 4; c++) st[c] = (floatx4){0.f, 0.f, 0.f, 0.f};
        __builtin_amdgcn_s_setprio(1);
        #pragma unroll
        for (int c = 0; c < 4; c++) {
            short8 ak0 = *reinterpret_cast<const short8*>(&Ksh[cur][(c * 2 + 0) * 512 + lane * 8]);
            short8 ak1 = *reinterpret_cast<const short8*>(&Ksh[cur][(c * 2 + 1) * 512 + lane * 8]);
            st[c] = __builtin_amdgcn_mfma_f32_16x16x32_bf16(ak0, bq[0], st[c], 0, 0, 0);
            st[c] = __builtin_amdgcn_mfma_f32_16x16x32_bf16(ak1, bq[1], st[c], 0, 0, 0);
        }
        __builtin_amdgcn_s_setprio(0);
        // causal mask: key = kbase + c*16 + quad*4 + r, q = qw + l15
        if (kbase + 63 > qw) {                   // wave-uniform
            int base0 = kbase + quad * 4 - qw - l15;
            #pragma unroll
            for (int c = 0; c < 4; c++) {
                int base = base0 + c * 16;
                #pragma unroll
                for (int r = 0; r < 4; r++)
                    if (base + r > 0) st[c][r] = -1e30f;
            }
        }
        // p = 2^s: raw v_exp_f32 (masked -> 2^-1e30 = 0); per-lane denom; pack Ps
        #pragma unroll
        for (int c = 0; c < 4; c++) {
            float p0 = __builtin_amdgcn_exp2f(st[c][0]);
            float p1 = __builtin_amdgcn_exp2f(st[c][1]);
            float p2 = __builtin_amdgcn_exp2f(st[c][2]);
            float p3 = __builtin_amdgcn_exp2f(st[c][3]);
            l_part += (p0 + p1) + (p2 + p3);
            int elem = (c >> 1) * 512
                     + (l15 + 16 * ((c & 1) * 2 + (quad >> 1))) * 8 + (quad & 1) * 4;
            *reinterpret_cast<uint2*>(&Ps[wave][elem]) = pack4bf(p0, p1, p2, p3);
        }
        // Oᵀ += Vᵀ·Pᵀ: A-frag = Vᵀ d-rows, B-frag = Pᵀ (both linear b128)
        __builtin_amdgcn_s_setprio(1);
        #pragma unroll
        for (int s = 0; s < 2; s++) {
            short8 bp = *reinterpret_cast<const short8*>(&Ps[wave][s * 512 + lane * 8]);
            #pragma unroll
            for (int c = 0; c < 4; c++) {
                short8 av = *reinterpret_cast<const short8*>(&Vsh[cur][(c * 2 + s) * 512 + lane * 8]);
                acc_o[c] = __builtin_amdgcn_mfma_f32_16x16x32_bf16(av, bp, acc_o[c], 0, 0, 0);
            }
        }
        __builtin_amdgcn_s_setprio(0);

        __syncthreads();                         // readers done + prefetch drained
        cur ^= 1;
    }
    // denom partial: sum the 4 quad-lanes holding this q-row
    float l = l_part;
    l += __shfl_xor(l, 16, 64);
    l += __shfl_xor(l, 32, 64);
    const int q = qw + l15;
    if (qt < 32) {
        // single-chunk: finalize here. O row-major [SEQ][INNER].
        float rcp = 1.0f / l;
        #pragma unroll
        for (int c = 0; c < 4; c++) {
            uint2 v = pack4bf(acc_o[c][0] * rcp, acc_o[c][1] * rcp,
                              acc_o[c][2] * rcp, acc_o[c][3] * rcp);
            *reinterpret_cast<uint2*>(Oa + (size_t)q * INNER + head * DHEAD + c * 16 + quad * 4) = v;
        }
    } else {
        // split: write unnormalized fp32 partials (q in [2048,4096))
        float* Op = ck ? Op1 : Op0;
        float* Lp = ck ? L1 : L0;
        if (quad == 0) Lp[head * 2048 + (q - 2048)] = l;
        #pragma unroll
        for (int c = 0; c < 4; c++)
            *reinterpret_cast<floatx4*>(
                Op + (size_t)(q - 2048) * INNER + head * DHEAD + c * 16 + quad * 4) = acc_o[c];
    }
}

// ---------------- combine: rows 2048..4095 = (O0+O1)/(l0+l1) -> bf16 Oa ----------------
__global__ __launch_bounds__(256) void combine_kernel(
        const float* __restrict__ Op0, const float* __restrict__ Op1,
        const float* __restrict__ L0, const float* __restrict__ L1,
        bf16* __restrict__ Oa) {
    int idx = blockIdx.x * 256 + threadIdx.x;    // 524288 threads, 4 floats each
    int row = idx >> 8;                          // 0..2047 (q = 2048 + row)
    int c4 = (idx & 255) * 4;                    // col base
    int head = c4 >> 6;
    float l = L0[head * 2048 + row] + L1[head * 2048 + row];
    float rcp = 1.0f / l;
    float4 a = *reinterpret_cast<const float4*>(Op0 + (size_t)row * INNER + c4);
    float4 b = *reinterpret_cast<const float4*>(Op1 + (size_t)row * INNER + c4);
    uint2 v = pack4bf((a.x + b.x) * rcp, (a.y + b.y) * rcp,
                      (a.z + b.z) * rcp, (a.w + b.w) * rcp);
    *reinterpret_cast<uint2*>(Oa + (size_t)(2048 + row) * INNER + c4) = v;
}

extern "C" void kernel_launch(void* const* d_in, const int* in_sizes, int n_in,
                              void* d_out, int out_size, void* d_ws, size_t ws_size,
                              hipStream_t stream) {
    const float* x  = (const float*)d_in[0];
    const float* Wq = (const float*)d_in[1];
    const float* Wk = (const float*)d_in[2];
    const float* Wv = (const float*)d_in[3];
    const float* Wo = (const float*)d_in[4];
    const float* bo = (const float*)d_in[5];
    float* out = (float*)d_out;

    char* ws = (char*)d_ws;
    size_t off = 0;
    bf16* xb  = (bf16*)(ws + off); off += (size_t)SEQ * DIM * 2;
    bf16* Wqt = (bf16*)(ws + off); off += (size_t)DIM * INNER * 2;
    bf16* Wkt = (bf16*)(ws + off); off += (size_t)DIM * INNER * 2;
    bf16* Wvt = (bf16*)(ws + off); off += (size_t)DIM * INNER * 2;
    bf16* Wot = (bf16*)(ws + off); off += (size_t)INNER * DIM * 2;
    bf16* Qh  = (bf16*)(ws + off); off += (size_t)NHEADS * SEQ * DHEAD * 2;
    bf16* Kh  = (bf16*)(ws + off); off += (size_t)NHEADS * SEQ * DHEAD * 2;
    bf16* Vtr = (bf16*)(ws + off); off += (size_t)NHEADS * DHEAD * SEQ * 2;
    bf16* Oa  = (bf16*)(ws + off); off += (size_t)SEQ * INNER * 2;
    float* Op0 = (float*)(ws + off); off += (size_t)(SEQ / 2) * INNER * 4;  // 8 MB
    float* Op1 = (float*)(ws + off); off += (size_t)(SEQ / 2) * INNER * 4;  // 8 MB
    float* L0  = (float*)(ws + off); off += (size_t)NHEADS * (SEQ / 2) * 4;
    float* L1  = (float*)(ws + off); off += (size_t)NHEADS * (SEQ / 2) * 4;  // ~64.5 MB total

    prep_kernel<<<dim3(32, 32, 5), dim3(32, 8), 0, stream>>>(x, Wq, Wk, Wv, Wo,
                                                             xb, Wqt, Wkt, Wvt, Wot);
    qkv_gemm_kernel<<<dim3(8, 32, 3), 256, 0, stream>>>(xb, Wqt, Wkt, Wvt, Qh, Kh, Vtr);
    attention_kernel<<<1536, 256, 0, stream>>>(Qh, Kh, Vtr, Oa, Op0, Op1, L0, L1);
    combine_kernel<<<2048, 256, 0, stream>>>(Op0, Op1, L0, L1, Oa);
    out_gemm_kernel<<<dim3(8, 32), 256, 0, stream>>>(Oa, Wot, bo, out);
}